// Round 1
// baseline (331.348 us; speedup 1.0000x reference)
//
#include <hip/hip_runtime.h>

#define D 64

// ---------------------------------------------------------------------------
// Phase 1: scatter-add  neighbor[dst] += w * features[src]
// thread-per-(edge,dim): 64 consecutive threads handle one edge, so
// edge_src/edge_dst/edge_weight loads are uniform per 64-lane group and the
// feature read + atomic write are coalesced 256B per wave.
// ---------------------------------------------------------------------------
__global__ __launch_bounds__(256) void scatter_kernel(
    const float* __restrict__ features,
    const int*   __restrict__ edge_src,
    const int*   __restrict__ edge_dst,
    const float* __restrict__ edge_weight,
    float*       __restrict__ neighbor,
    long long total)   // n_edges * 64
{
    long long idx = (long long)blockIdx.x * blockDim.x + threadIdx.x;
    if (idx >= total) return;
    int e = (int)(idx >> 6);
    int d = (int)(idx & 63);
    int src = edge_src[e];
    int dst = edge_dst[e];
    float w = edge_weight[e];
    float f = features[(long long)src * D + d];
    atomicAdd(&neighbor[(long long)dst * D + d], w * f);
}

// ---------------------------------------------------------------------------
// Phase 2: out = normalize( [features | neighbor] @ W^T + b )
// One wave per node. Lane o computes output channel o.
// W [64][128] staged transposed into LDS as Wt[k][o] with +1 pad: at fixed k,
// lanes o=0..63 read consecutive floats -> conflict-free (2 lanes/bank, free).
// Combined row is broadcast across the wave via __shfl.
// ---------------------------------------------------------------------------
__global__ __launch_bounds__(256) void gemm_norm_kernel(
    const float* __restrict__ features,
    const float* __restrict__ neighbor,
    const float* __restrict__ W,    // [64][128] row-major
    const float* __restrict__ b,    // [64]
    float*       __restrict__ out,  // [n][64]
    int n_nodes)
{
    __shared__ float Wt[128][D + 1];
    int tid = threadIdx.x;

    // stage W transposed (one-time per block; write conflicts broken by pad)
    for (int idx = tid; idx < D * 128; idx += 256) {
        int o = idx >> 7;        // 0..63
        int k = idx & 127;       // 0..127
        Wt[k][o] = W[idx];
    }
    __syncthreads();

    int lane  = tid & 63;
    int wave  = tid >> 6;
    int gwave = blockIdx.x * 4 + wave;
    int nwaves = gridDim.x * 4;
    float bias = b[lane];

    for (int i = gwave; i < n_nodes; i += nwaves) {
        float cf = features[(long long)i * D + lane];
        float cn = neighbor[(long long)i * D + lane];
        float acc = bias;
        #pragma unroll
        for (int k = 0; k < 64; ++k) {
            acc = fmaf(__shfl(cf, k, 64), Wt[k][lane], acc);
        }
        #pragma unroll
        for (int k = 0; k < 64; ++k) {
            acc = fmaf(__shfl(cn, k, 64), Wt[64 + k][lane], acc);
        }
        // row L2 norm across the 64 lanes (butterfly over full wave)
        float s = acc * acc;
        #pragma unroll
        for (int m = 32; m >= 1; m >>= 1) s += __shfl_xor(s, m, 64);
        float norm = sqrtf(s);
        out[(long long)i * D + lane] = acc / fmaxf(norm, 1e-12f);
    }
}

extern "C" void kernel_launch(void* const* d_in, const int* in_sizes, int n_in,
                              void* d_out, int out_size, void* d_ws, size_t ws_size,
                              hipStream_t stream) {
    const float* features    = (const float*)d_in[0];
    const int*   edge_src    = (const int*)d_in[1];
    const int*   edge_dst    = (const int*)d_in[2];
    const float* edge_weight = (const float*)d_in[3];
    const float* W           = (const float*)d_in[4];
    const float* b           = (const float*)d_in[5];
    float*       out         = (float*)d_out;

    int n_nodes = in_sizes[0] / D;
    int n_edges = in_sizes[1];

    float* neighbor = (float*)d_ws;   // [n_nodes][64] accumulator

    // workspace is re-poisoned to 0xAA before every call -> zero it each time
    hipMemsetAsync(neighbor, 0, (size_t)n_nodes * D * sizeof(float), stream);

    long long total = (long long)n_edges * D;
    int blocks = (int)((total + 255) / 256);
    scatter_kernel<<<blocks, 256, 0, stream>>>(features, edge_src, edge_dst,
                                               edge_weight, neighbor, total);

    gemm_norm_kernel<<<1024, 256, 0, stream>>>(features, neighbor, W, b, out,
                                               n_nodes);
}